// Round 7
// baseline (293.474 us; speedup 1.0000x reference)
//
#include <hip/hip_runtime.h>
#include <stdint.h>

#define T_SEQ 2048
#define DM    2048
#define NH    16
#define NKV   4
#define HD    128
#define MROWS 4096          // B*T
#define NQKV  3072          // 16*128 + 4*128 + 4*128

typedef unsigned short u16;
typedef __bf16 bf16x8 __attribute__((ext_vector_type(8)));
typedef float  f32x4  __attribute__((ext_vector_type(4)));

__device__ __forceinline__ u16 f2b(float f) {
  union { float f; unsigned u; } v; v.f = f;
  return (u16)((v.u + 0x7fffu + ((v.u >> 16) & 1u)) >> 16);
}
__device__ __forceinline__ float b2f(u16 u) {
  union { unsigned u; float f; } v; v.u = ((unsigned)u) << 16;
  return v.f;
}
// async global->LDS, 16B per lane; LDS dest = wave-uniform base + lane*16
__device__ __forceinline__ void gl_lds16(const u16* g, u16* l) {
  __builtin_amdgcn_global_load_lds(
      (__attribute__((address_space(1))) void*)g,
      (__attribute__((address_space(3))) void*)l, 16, 0, 0);
}
__device__ __forceinline__ void storev(float* p, float v) { *p = v; }
__device__ __forceinline__ void storev(u16* p, float v)   { *p = f2b(v); }

// ---- fused prologue: x fp32->bf16 (blocks < 8192) + 4 weight transposes ----
__global__ __launch_bounds__(256) void k_pre(const float* __restrict__ x,
                                             const float* __restrict__ Wq,
                                             const float* __restrict__ Wk,
                                             const float* __restrict__ Wv,
                                             const float* __restrict__ Wo,
                                             u16* __restrict__ Xb,
                                             u16* __restrict__ WT,
                                             u16* __restrict__ Wot) {
  int bid = blockIdx.x;
  int tid = threadIdx.x;
  if (bid < 8192) {
    int i = (bid * 256 + tid) * 4;
    float4 v = *(const float4*)(x + i);
    ushort4 r;
    r.x = f2b(v.x); r.y = f2b(v.y); r.z = f2b(v.z); r.w = f2b(v.w);
    *(ushort4*)(Xb + i) = r;
    return;
  }
  __shared__ float tl[32][33];
  int zz = bid - 8192;          // 0..10239
  int z = zz >> 6;              // 0..159
  int ky = zz & 63;             // k-tile 0..63
  const float* in; u16* out; int Nd, xt;
  if (z < 64)      { in = Wq; out = WT;               Nd = 2048; xt = z; }
  else if (z < 80) { in = Wk; out = WT + 2048 * 2048; Nd = 512;  xt = z - 64; }
  else if (z < 96) { in = Wv; out = WT + 2560 * 2048; Nd = 512;  xt = z - 80; }
  else             { in = Wo; out = Wot;              Nd = 2048; xt = z - 96; }
  int n0 = xt * 32, k0 = ky * 32;
  int tx = tid & 31, ty = tid >> 5;
#pragma unroll
  for (int i = 0; i < 32; i += 8)
    tl[ty + i][tx] = in[(long)(k0 + ty + i) * Nd + n0 + tx];
  __syncthreads();
#pragma unroll
  for (int i = 0; i < 32; i += 8)
    out[(long)(n0 + ty + i) * 2048 + k0 + tx] = f2b(tl[tx][ty + i]);
}

// ---- C[M][N] = A[M][K] * Bt[N][K]^T  (128^2 tile, BK=64) ----
// Proven single-buffered 2-barrier loop, 32 K-iterations (half the drains of
// BK=32; r6: -16.5us total). 8-slot/row XOR swizzle; wave->column remap puts
// both halves of a rope pair (d, d+64) in one thread for MODE 1.
//   MODE 0: plain store C[M][N] (out-projection).
//   MODE 1: QKV fused RoPE epilogue -> Qn/Kb/Vc final layouts.
template <int MODE, typename OutT>
__global__ __launch_bounds__(256) void k_gemm(const u16* __restrict__ A,
                                              const u16* __restrict__ Bt,
                                              OutT* __restrict__ C,
                                              u16* __restrict__ Qn,
                                              u16* __restrict__ Kb,
                                              u16* __restrict__ Vc,
                                              int M, int N, int K) {
  __shared__ __align__(16) u16 As[128 * 64];
  __shared__ __align__(16) u16 Bs[128 * 64];
  const int tid = threadIdx.x;
  const int wv = tid >> 6, lane = tid & 63;
  const int quad = lane >> 4, ln = lane & 15;
  const int wm = wv & 1, wn = wv >> 1;
  const long m0 = (long)blockIdx.x * 128;
  const long n0 = (long)blockIdx.y * 128;
  f32x4 acc[4][4] = {};
  for (int k0 = 0; k0 < K; k0 += 64) {
#pragma unroll
    for (int r = 0; r < 4; ++r) {
      int c = r * 256 + tid;              // linear LDS chunk id; row = c>>3
      int gc = (c & 7) ^ ((c >> 3) & 7);  // swizzled global chunk col
      gl_lds16(A  + (m0 + (c >> 3)) * K + k0 + gc * 8, &As[(r * 256 + wv * 64) * 8]);
      gl_lds16(Bt + (n0 + (c >> 3)) * K + k0 + gc * 8, &Bs[(r * 256 + wv * 64) * 8]);
    }
    __syncthreads();
#pragma unroll
    for (int kk = 0; kk < 2; ++kk) {
      const int rs = ((kk << 2) + quad) ^ (ln & 7);  // swizzled read slot
      bf16x8 af[4], bg[4];
#pragma unroll
      for (int i = 0; i < 4; ++i)
        af[i] = *(const bf16x8*)&As[(wm * 64 + i * 16 + ln) * 64 + rs * 8];
#pragma unroll
      for (int j = 0; j < 4; ++j)
        bg[j] = *(const bf16x8*)&Bs[(wn * 32 + (j >> 1) * 64 + (j & 1) * 16 + ln) * 64 + rs * 8];
#pragma unroll
      for (int i = 0; i < 4; ++i)
#pragma unroll
        for (int j = 0; j < 4; ++j)
          acc[i][j] = __builtin_amdgcn_mfma_f32_16x16x32_bf16(af[i], bg[j], acc[i][j], 0, 0, 0);
    }
    __syncthreads();
  }
  if constexpr (MODE == 0) {
#pragma unroll
    for (int i = 0; i < 4; ++i) {
      long row = m0 + wm * 64 + i * 16 + quad * 4;
#pragma unroll
      for (int j = 0; j < 4; ++j) {
        long col = n0 + wn * 32 + (j >> 1) * 64 + (j & 1) * 16 + ln;
#pragma unroll
        for (int r = 0; r < 4; ++r)
          storev(&C[(row + r) * N + col], acc[i][j][r]);
      }
    }
  } else {
    const int nt = blockIdx.y;          // 0..15 Q head | 16..19 K | 20..23 V
    if (nt < 20) {
      const int isQ = nt < 16;
      const int head = isQ ? nt : nt - 16;
      u16* o = isQ ? Qn : Kb;
      const int nh = isQ ? NH : NKV;
      const float qs = isQ ? 0.12751745f : 1.0f;  // (1/sqrt(128))*log2(e)
      const int d0 = wn * 32 + ln;                // j=0 pair base
      const float inv0 = __expf(-0.14391156f * (float)d0);        // 10000^(-d/64)
      const float inv1 = __expf(-0.14391156f * (float)(d0 + 16)); // j=1
#pragma unroll
      for (int i = 0; i < 4; ++i) {
#pragma unroll
        for (int r = 0; r < 4; ++r) {
          long row = m0 + wm * 64 + i * 16 + quad * 4 + r;
          int b = (int)(row >> 11), t = (int)(row & (T_SEQ - 1));
          long ob = ((long)(b * nh + head) * T_SEQ + t) * HD;
#pragma unroll
          for (int j = 0; j < 2; ++j) {
            int d = d0 + j * 16;
            float q1 = acc[i][j][r], q2 = acc[i][j + 2][r];
            float sn, cs;
            __sincosf((float)t * (j ? inv1 : inv0), &sn, &cs);
            o[ob + d]      = f2b((q1 * cs - q2 * sn) * qs);
            o[ob + d + 64] = f2b((q2 * cs + q1 * sn) * qs);
          }
        }
      }
    } else {
      const int kv = nt - 20;
#pragma unroll
      for (int i = 0; i < 4; ++i) {
#pragma unroll
        for (int r = 0; r < 4; ++r) {
          long row = m0 + wm * 64 + i * 16 + quad * 4 + r;
          int b = (int)(row >> 11), t = (int)(row & (T_SEQ - 1));
          long ob = ((long)(b * NKV + kv) * T_SEQ + t) * HD;
#pragma unroll
          for (int j = 0; j < 4; ++j) {
            int d = wn * 32 + (j >> 1) * 64 + (j & 1) * 16 + ln;
            Vc[ob + d] = f2b(acc[i][j][r]);
          }
        }
      }
    }
  }
}

// ---- Vc [B,KV,T,HD] -> Vt [B,KV,HD,T], vectorized 64x64 tile transpose ----
__global__ __launch_bounds__(256) void k_vt(const u16* __restrict__ Vc,
                                            u16* __restrict__ Vt) {
  __shared__ u16 tl[64][68];   // 136B stride: 8B-aligned, conflicts negligible
  int bkv = blockIdx.z;
  int t0 = blockIdx.x * 64, d0 = blockIdx.y * 64;
  int tx = threadIdx.x & 15, ty = threadIdx.x >> 4;
  const u16* src = Vc + ((long)bkv * T_SEQ + t0) * HD + d0;
#pragma unroll
  for (int ii = 0; ii < 4; ++ii) {
    ushort4 v = *(const ushort4*)&src[(ty + 16 * ii) * HD + tx * 4];
    tl[ty + 16 * ii][tx * 4 + 0] = v.x;
    tl[ty + 16 * ii][tx * 4 + 1] = v.y;
    tl[ty + 16 * ii][tx * 4 + 2] = v.z;
    tl[ty + 16 * ii][tx * 4 + 3] = v.w;
  }
  __syncthreads();
  u16* dst = Vt + ((long)bkv * HD + d0) * T_SEQ + t0;
#pragma unroll
  for (int ii = 0; ii < 4; ++ii) {
    int dr = ty + 16 * ii;
    ushort4 o;
    o.x = tl[tx * 4 + 0][dr];
    o.y = tl[tx * 4 + 1][dr];
    o.z = tl[tx * 4 + 2][dr];
    o.w = tl[tx * 4 + 3][dr];
    *(ushort4*)&dst[(long)dr * T_SEQ + tx * 4] = o;
  }
}

// ---- per-tile fixed-rebase P emit (one 16x16 score tile) ----
// Called inline right after S[nt] is accumulated so the exp2/ds_write of
// tile nt overlap the K-frag reads + MFMAs of tile nt+1 (sm-split, m214).
__device__ __forceinline__ void p_emit1(const f32x4& S1, int nt,
                                        u16* __restrict__ Pb,
                                        int quad, int ln, bool diag, int mrow) {
#pragma unroll
  for (int r = 0; r < 4; ++r) {
    float v = S1[r];
    v = (!diag || (nt * 16 + ln <= mrow + r)) ? v : -1e30f;
    float pv = exp2f(v - 8.0f);
    int row = quad * 4 + r;
    int chnk = (nt * 2 + (ln >> 3)) ^ (row & 7);
    *(__bf16*)&Pb[row * 64 + chnk * 8 + (ln & 7)] = (__bf16)pv;
  }
}

// ---- causal GQA flash attention: pair-balanced, fixed-rebase softmax ----
// K/V LDS double-buffered (80KB, 2 blocks/CU); stage(kt+1) before compute;
// one vmcnt(0)+s_barrier per iteration; setprio around MFMA regions.
// ROUND-7: P-emit inlined per nt-tile inside the QK^T loop (softmax TRANS/
// VALU hidden under MFMA); Sh/Sl arrays eliminated (-32 VGPR).
__global__ __launch_bounds__(256, 2) void k_attn(const u16* __restrict__ Q,
                                                 const u16* __restrict__ Kg,
                                                 const u16* __restrict__ Vt,
                                                 u16* __restrict__ Og) {
  __shared__ __align__(16) u16 Ks[2][64 * 128];   // [key][hd], swizzled chunks
  __shared__ __align__(16) u16 Vs[2][128 * 64];   // [hd][key], swizzled chunks
  __shared__ __align__(16) u16 Ps[4][2][16 * 64]; // per-wave, per-strip P
  const int tid = threadIdx.x;
  const int wv = tid >> 6, lane = tid & 63;
  const int quad = lane >> 4, ln = lane & 15;
  const int bh = blockIdx.y;
  const int b = bh >> 4, h = bh & 15;
  const int kvh = h >> 2;
  const int p = blockIdx.x;
  const int thi = 31 - p, tlo = p;
  const int qhi = thi * 64 + wv * 16;   // global q-row base, hi strip
  const int qlo = tlo * 64 + wv * 16;
  const int mrow = wv * 16 + quad * 4;  // diag-mask row base (block-local)

  bf16x8 qfh[4], qfl[4];
  {
    const u16* qp = Q + ((long)bh * T_SEQ + qhi + ln) * HD + quad * 8;
#pragma unroll
    for (int s = 0; s < 4; ++s) qfh[s] = *(const bf16x8*)(qp + s * 32);
    qp = Q + ((long)bh * T_SEQ + qlo + ln) * HD + quad * 8;
#pragma unroll
    for (int s = 0; s < 4; ++s) qfl[s] = *(const bf16x8*)(qp + s * 32);
  }
  bf16x8 onesb;
#pragma unroll
  for (int i = 0; i < 8; ++i) onesb[i] = (__bf16)1.0f;

  f32x4 lh = {0.f, 0.f, 0.f, 0.f}, ll = {0.f, 0.f, 0.f, 0.f};
  f32x4 oh[8] = {}, ol[8] = {};

  const u16* Kb = Kg + (long)(b * NKV + kvh) * T_SEQ * HD;
  const u16* Vb = Vt + (long)(b * NKV + kvh) * HD * T_SEQ;

  auto stageKV = [&](int kt, int idx) {
    const int k0 = kt * 64;
#pragma unroll
    for (int r = 0; r < 4; ++r) {
      int s = r * 256 + tid;
      gl_lds16(Kb + (long)(k0 + (s >> 4)) * HD + (((s & 15) ^ ((s >> 4) & 15)) << 3),
               &Ks[idx][(r * 256 + wv * 64) * 8]);
      gl_lds16(Vb + (long)(s >> 3) * T_SEQ + k0 + (((s & 7) ^ ((s >> 3) & 7)) << 3),
               &Vs[idx][(r * 256 + wv * 64) * 8]);
    }
  };

  stageKV(0, 0);
  asm volatile("s_waitcnt vmcnt(0)" ::: "memory");
  __builtin_amdgcn_s_barrier();

  for (int kt = 0; kt <= thi; ++kt) {
    const int cur = kt & 1;
    if (kt < thi) stageKV(kt + 1, cur ^ 1);
    const u16* Ksc = Ks[cur];
    const u16* Vsc = Vs[cur];
    const bool lo_act = (kt <= tlo);
    const bool dh = (kt == thi), dl = (kt == tlo);
    // QK^T + inline per-tile softmax emit (both strips, shared K fragments)
    __builtin_amdgcn_s_setprio(1);
#pragma unroll
    for (int nt = 0; nt < 4; ++nt) {
      bf16x8 kb[4];
      const u16* kp = &Ksc[(nt * 16 + ln) * 128];
#pragma unroll
      for (int ss = 0; ss < 4; ++ss)
        kb[ss] = *(const bf16x8*)(kp + (((quad + 4 * ss) ^ ln) << 3));
      f32x4 s = {0.f, 0.f, 0.f, 0.f};
#pragma unroll
      for (int ss = 0; ss < 4; ++ss)
        s = __builtin_amdgcn_mfma_f32_16x16x32_bf16(qfh[ss], kb[ss], s, 0, 0, 0);
      f32x4 t = {0.f, 0.f, 0.f, 0.f};
      if (lo_act) {
#pragma unroll
        for (int ss = 0; ss < 4; ++ss)
          t = __builtin_amdgcn_mfma_f32_16x16x32_bf16(qfl[ss], kb[ss], t, 0, 0, 0);
      }
      p_emit1(s, nt, &Ps[wv][0][0], quad, ln, dh, mrow);
      if (lo_act) p_emit1(t, nt, &Ps[wv][1][0], quad, ln, dl, mrow);
    }
    __builtin_amdgcn_s_setprio(0);
    // drain P ds_writes before same-wave cross-lane readback
    asm volatile("s_waitcnt lgkmcnt(0)" ::: "memory");
    bf16x8 pfh[2], pfl[2];
#pragma unroll
    for (int ss = 0; ss < 2; ++ss)
      pfh[ss] = *(const bf16x8*)&Ps[wv][0][ln * 64 + (((ss * 4 + quad) ^ (ln & 7)) << 3)];
    if (lo_act) {
#pragma unroll
      for (int ss = 0; ss < 2; ++ss)
        pfl[ss] = *(const bf16x8*)&Ps[wv][1][ln * 64 + (((ss * 4 + quad) ^ (ln & 7)) << 3)];
    }
    __builtin_amdgcn_s_setprio(1);
    lh = __builtin_amdgcn_mfma_f32_16x16x32_bf16(pfh[0], onesb, lh, 0, 0, 0);
    lh = __builtin_amdgcn_mfma_f32_16x16x32_bf16(pfh[1], onesb, lh, 0, 0, 0);
    if (lo_act) {
      ll = __builtin_amdgcn_mfma_f32_16x16x32_bf16(pfl[0], onesb, ll, 0, 0, 0);
      ll = __builtin_amdgcn_mfma_f32_16x16x32_bf16(pfl[1], onesb, ll, 0, 0, 0);
    }
#pragma unroll
    for (int dt = 0; dt < 8; ++dt) {
      bf16x8 vb[2];
      const u16* vp = &Vsc[(dt * 16 + ln) * 64];
#pragma unroll
      for (int ss = 0; ss < 2; ++ss)
        vb[ss] = *(const bf16x8*)(vp + (((quad + 4 * ss) ^ (ln & 7)) << 3));
#pragma unroll
      for (int ss = 0; ss < 2; ++ss)
        oh[dt] = __builtin_amdgcn_mfma_f32_16x16x32_bf16(pfh[ss], vb[ss], oh[dt], 0, 0, 0);
      if (lo_act) {
#pragma unroll
        for (int ss = 0; ss < 2; ++ss)
          ol[dt] = __builtin_amdgcn_mfma_f32_16x16x32_bf16(pfl[ss], vb[ss], ol[dt], 0, 0, 0);
      }
    }
    __builtin_amdgcn_s_setprio(0);
    asm volatile("s_waitcnt vmcnt(0)" ::: "memory");
    __builtin_amdgcn_s_barrier();
  }
  float rh[4], rl[4];
#pragma unroll
  for (int r = 0; r < 4; ++r) { rh[r] = 1.f / lh[r]; rl[r] = 1.f / ll[r]; }
#pragma unroll
  for (int dt = 0; dt < 8; ++dt)
#pragma unroll
    for (int r = 0; r < 4; ++r) {
      long rowh = (long)b * T_SEQ + qhi + quad * 4 + r;
      long rowl = (long)b * T_SEQ + qlo + quad * 4 + r;
      Og[rowh * (NH * HD) + h * HD + dt * 16 + ln] = f2b(oh[dt][r] * rh[r]);
      Og[rowl * (NH * HD) + h * HD + dt * 16 + ln] = f2b(ol[dt][r] * rl[r]);
    }
}

extern "C" void kernel_launch(void* const* d_in, const int* in_sizes, int n_in,
                              void* d_out, int out_size, void* d_ws, size_t ws_size,
                              hipStream_t stream) {
  const float* x  = (const float*)d_in[0];
  const float* Wq = (const float*)d_in[1];
  const float* Wk = (const float*)d_in[2];
  const float* Wv = (const float*)d_in[3];
  const float* Wo = (const float*)d_in[4];
  float* out = (float*)d_out;
  char* ws = (char*)d_ws;
  // workspace layout (bytes) -- within the original 71.3MB footprint
  u16* WT  = (u16*)(ws + 0);          // [3072][2048] bf16  (Wq^T | Wk^T | Wv^T)
  u16* Wot = (u16*)(ws + 12582912);   // [2048][2048] bf16
  u16* Vc  = (u16*)(ws + 20971520);   // [B,NKV,T,HD] bf16 (4.2MB, pre-transpose V)
  u16* Qn  = (u16*)(ws + 25165824);   // [B,NH,T,HD] bf16 (16.8MB, roped+scaled Q)
  u16* Xb  = (u16*)(ws + 46137344);   // [4096][2048] bf16 x ; later attn output
  u16* Kb  = (u16*)(ws + 62914560);   // [B,NKV,T,HD] bf16 (roped K)
  u16* Vtb = (u16*)(ws + 67108864);   // [B,NKV,HD,T] bf16
  u16* attn = Xb;   // alias: Xb dead after QKV GEMM (rope now fused there)

  // x convert + all weight transposes, one launch
  k_pre<<<18432, 256, 0, stream>>>(x, Wq, Wk, Wv, Wo, Xb, WT, Wot);

  // QKV projection with fused RoPE epilogue: writes Qn, Kb, Vc directly
  k_gemm<1, u16><<<dim3(32, 24), 256, 0, stream>>>(
      Xb, WT, (u16*)nullptr, Qn, Kb, Vc, MROWS, NQKV, DM);

  k_vt<<<dim3(32, 2, 8), 256, 0, stream>>>(Vc, Vtb);

  k_attn<<<dim3(16, 32), 256, 0, stream>>>(Qn, Kb, Vtb, attn);

  // output projection
  k_gemm<0, float><<<dim3(32, 16), 256, 0, stream>>>(
      attn, Wot, out, nullptr, nullptr, nullptr, MROWS, DM, 2048);
}

// Round 8
// 283.618 us; speedup vs baseline: 1.0348x; 1.0348x over previous
//
#include <hip/hip_runtime.h>
#include <stdint.h>

#define T_SEQ 2048
#define DM    2048
#define NH    16
#define NKV   4
#define HD    128
#define MROWS 4096          // B*T
#define NQKV  3072          // 16*128 + 4*128 + 4*128

typedef unsigned short u16;
typedef __bf16 bf16x8 __attribute__((ext_vector_type(8)));
typedef float  f32x4  __attribute__((ext_vector_type(4)));

__device__ __forceinline__ u16 f2b(float f) {
  union { float f; unsigned u; } v; v.f = f;
  return (u16)((v.u + 0x7fffu + ((v.u >> 16) & 1u)) >> 16);
}
__device__ __forceinline__ float b2f(u16 u) {
  union { unsigned u; float f; } v; v.u = ((unsigned)u) << 16;
  return v.f;
}
// async global->LDS, 16B per lane; LDS dest = wave-uniform base + lane*16
__device__ __forceinline__ void gl_lds16(const u16* g, u16* l) {
  __builtin_amdgcn_global_load_lds(
      (__attribute__((address_space(1))) void*)g,
      (__attribute__((address_space(3))) void*)l, 16, 0, 0);
}
__device__ __forceinline__ void storev(float* p, float v) { *p = v; }
__device__ __forceinline__ void storev(u16* p, float v)   { *p = f2b(v); }

// ---- fused prologue: x fp32->bf16 (blocks < 8192) + 4 weight transposes ----
__global__ __launch_bounds__(256) void k_pre(const float* __restrict__ x,
                                             const float* __restrict__ Wq,
                                             const float* __restrict__ Wk,
                                             const float* __restrict__ Wv,
                                             const float* __restrict__ Wo,
                                             u16* __restrict__ Xb,
                                             u16* __restrict__ WT,
                                             u16* __restrict__ Wot) {
  int bid = blockIdx.x;
  int tid = threadIdx.x;
  if (bid < 8192) {
    int i = (bid * 256 + tid) * 4;
    float4 v = *(const float4*)(x + i);
    ushort4 r;
    r.x = f2b(v.x); r.y = f2b(v.y); r.z = f2b(v.z); r.w = f2b(v.w);
    *(ushort4*)(Xb + i) = r;
    return;
  }
  __shared__ float tl[32][33];
  int zz = bid - 8192;          // 0..10239
  int z = zz >> 6;              // 0..159
  int ky = zz & 63;             // k-tile 0..63
  const float* in; u16* out; int Nd, xt;
  if (z < 64)      { in = Wq; out = WT;               Nd = 2048; xt = z; }
  else if (z < 80) { in = Wk; out = WT + 2048 * 2048; Nd = 512;  xt = z - 64; }
  else if (z < 96) { in = Wv; out = WT + 2560 * 2048; Nd = 512;  xt = z - 80; }
  else             { in = Wo; out = Wot;              Nd = 2048; xt = z - 96; }
  int n0 = xt * 32, k0 = ky * 32;
  int tx = tid & 31, ty = tid >> 5;
#pragma unroll
  for (int i = 0; i < 32; i += 8)
    tl[ty + i][tx] = in[(long)(k0 + ty + i) * Nd + n0 + tx];
  __syncthreads();
#pragma unroll
  for (int i = 0; i < 32; i += 8)
    out[(long)(n0 + ty + i) * 2048 + k0 + tx] = f2b(tl[tx][ty + i]);
}

// ---- C[M][N] = A[M][K] * Bt[N][K]^T  (128^2 tile, BK=64) ----
// Proven single-buffered 2-barrier loop, 32 K-iterations (half the drains of
// BK=32; r6: -16.5us total). 8-slot/row XOR swizzle; wave->column remap puts
// both halves of a rope pair (d, d+64) in one thread for MODE 1.
// ROUND-8: T1 XCD-aware block swizzle (nwg%8==0 for both grids): dispatch id
// d -> XCD-contiguous y-major tile id, so each XCD's blocks span ~4 row-tiles
// and the 512KB A row-panel stays L2-resident (FETCH 57MB vs 29MB ideal).
//   MODE 0: plain store C[M][N] (out-projection).
//   MODE 1: QKV fused RoPE epilogue -> Qn/Kb/Vc final layouts.
template <int MODE, typename OutT>
__global__ __launch_bounds__(256) void k_gemm(const u16* __restrict__ A,
                                              const u16* __restrict__ Bt,
                                              OutT* __restrict__ C,
                                              u16* __restrict__ Qn,
                                              u16* __restrict__ Kb,
                                              u16* __restrict__ Vc,
                                              int M, int N, int K) {
  __shared__ __align__(16) u16 As[128 * 64];
  __shared__ __align__(16) u16 Bs[128 * 64];
  const int tid = threadIdx.x;
  const int wv = tid >> 6, lane = tid & 63;
  const int quad = lane >> 4, ln = lane & 15;
  const int wm = wv & 1, wn = wv >> 1;
  // XCD swizzle: bijective since nwg % 8 == 0 (768 / 512 blocks)
  const int nwg = gridDim.x * gridDim.y;
  const int d = blockIdx.x + blockIdx.y * gridDim.x;   // HW dispatch order
  const int swz = (d & 7) * (nwg >> 3) + (d >> 3);
  const int bx = swz / gridDim.y;    // row tile (y-major: A-panel contiguous)
  const int by = swz % gridDim.y;    // col tile
  const long m0 = (long)bx * 128;
  const long n0 = (long)by * 128;
  f32x4 acc[4][4] = {};
  for (int k0 = 0; k0 < K; k0 += 64) {
#pragma unroll
    for (int r = 0; r < 4; ++r) {
      int c = r * 256 + tid;              // linear LDS chunk id; row = c>>3
      int gc = (c & 7) ^ ((c >> 3) & 7);  // swizzled global chunk col
      gl_lds16(A  + (m0 + (c >> 3)) * K + k0 + gc * 8, &As[(r * 256 + wv * 64) * 8]);
      gl_lds16(Bt + (n0 + (c >> 3)) * K + k0 + gc * 8, &Bs[(r * 256 + wv * 64) * 8]);
    }
    __syncthreads();
#pragma unroll
    for (int kk = 0; kk < 2; ++kk) {
      const int rs = ((kk << 2) + quad) ^ (ln & 7);  // swizzled read slot
      bf16x8 af[4], bg[4];
#pragma unroll
      for (int i = 0; i < 4; ++i)
        af[i] = *(const bf16x8*)&As[(wm * 64 + i * 16 + ln) * 64 + rs * 8];
#pragma unroll
      for (int j = 0; j < 4; ++j)
        bg[j] = *(const bf16x8*)&Bs[(wn * 32 + (j >> 1) * 64 + (j & 1) * 16 + ln) * 64 + rs * 8];
#pragma unroll
      for (int i = 0; i < 4; ++i)
#pragma unroll
        for (int j = 0; j < 4; ++j)
          acc[i][j] = __builtin_amdgcn_mfma_f32_16x16x32_bf16(af[i], bg[j], acc[i][j], 0, 0, 0);
    }
    __syncthreads();
  }
  if constexpr (MODE == 0) {
#pragma unroll
    for (int i = 0; i < 4; ++i) {
      long row = m0 + wm * 64 + i * 16 + quad * 4;
#pragma unroll
      for (int j = 0; j < 4; ++j) {
        long col = n0 + wn * 32 + (j >> 1) * 64 + (j & 1) * 16 + ln;
#pragma unroll
        for (int r = 0; r < 4; ++r)
          storev(&C[(row + r) * N + col], acc[i][j][r]);
      }
    }
  } else {
    const int nt = by;                  // 0..15 Q head | 16..19 K | 20..23 V
    if (nt < 20) {
      const int isQ = nt < 16;
      const int head = isQ ? nt : nt - 16;
      u16* o = isQ ? Qn : Kb;
      const int nh = isQ ? NH : NKV;
      const float qs = isQ ? 0.12751745f : 1.0f;  // (1/sqrt(128))*log2(e)
      const int d0 = wn * 32 + ln;                // j=0 pair base
      const float inv0 = __expf(-0.14391156f * (float)d0);        // 10000^(-d/64)
      const float inv1 = __expf(-0.14391156f * (float)(d0 + 16)); // j=1
#pragma unroll
      for (int i = 0; i < 4; ++i) {
#pragma unroll
        for (int r = 0; r < 4; ++r) {
          long row = m0 + wm * 64 + i * 16 + quad * 4 + r;
          int b = (int)(row >> 11), t = (int)(row & (T_SEQ - 1));
          long ob = ((long)(b * nh + head) * T_SEQ + t) * HD;
#pragma unroll
          for (int j = 0; j < 2; ++j) {
            int dd = d0 + j * 16;
            float q1 = acc[i][j][r], q2 = acc[i][j + 2][r];
            float sn, cs;
            __sincosf((float)t * (j ? inv1 : inv0), &sn, &cs);
            o[ob + dd]      = f2b((q1 * cs - q2 * sn) * qs);
            o[ob + dd + 64] = f2b((q2 * cs + q1 * sn) * qs);
          }
        }
      }
    } else {
      const int kv = nt - 20;
#pragma unroll
      for (int i = 0; i < 4; ++i) {
#pragma unroll
        for (int r = 0; r < 4; ++r) {
          long row = m0 + wm * 64 + i * 16 + quad * 4 + r;
          int b = (int)(row >> 11), t = (int)(row & (T_SEQ - 1));
          long ob = ((long)(b * NKV + kv) * T_SEQ + t) * HD;
#pragma unroll
          for (int j = 0; j < 4; ++j) {
            int dd = wn * 32 + (j >> 1) * 64 + (j & 1) * 16 + ln;
            Vc[ob + dd] = f2b(acc[i][j][r]);
          }
        }
      }
    }
  }
}

// ---- Vc [B,KV,T,HD] -> Vt [B,KV,HD,T], vectorized 64x64 tile transpose ----
__global__ __launch_bounds__(256) void k_vt(const u16* __restrict__ Vc,
                                            u16* __restrict__ Vt) {
  __shared__ u16 tl[64][68];   // 136B stride: 8B-aligned, conflicts negligible
  int bkv = blockIdx.z;
  int t0 = blockIdx.x * 64, d0 = blockIdx.y * 64;
  int tx = threadIdx.x & 15, ty = threadIdx.x >> 4;
  const u16* src = Vc + ((long)bkv * T_SEQ + t0) * HD + d0;
#pragma unroll
  for (int ii = 0; ii < 4; ++ii) {
    ushort4 v = *(const ushort4*)&src[(ty + 16 * ii) * HD + tx * 4];
    tl[ty + 16 * ii][tx * 4 + 0] = v.x;
    tl[ty + 16 * ii][tx * 4 + 1] = v.y;
    tl[ty + 16 * ii][tx * 4 + 2] = v.z;
    tl[ty + 16 * ii][tx * 4 + 3] = v.w;
  }
  __syncthreads();
  u16* dst = Vt + ((long)bkv * HD + d0) * T_SEQ + t0;
#pragma unroll
  for (int ii = 0; ii < 4; ++ii) {
    int dr = ty + 16 * ii;
    ushort4 o;
    o.x = tl[tx * 4 + 0][dr];
    o.y = tl[tx * 4 + 1][dr];
    o.z = tl[tx * 4 + 2][dr];
    o.w = tl[tx * 4 + 3][dr];
    *(ushort4*)&dst[(long)dr * T_SEQ + tx * 4] = o;
  }
}

// ---- fixed-rebase P emit for one 16x64 score strip (batched, r6-proven) ----
template <bool DIAG>
__device__ __forceinline__ void p_emit(f32x4 (&S)[4], u16* __restrict__ Pb,
                                       int quad, int ln, int mrow) {
#pragma unroll
  for (int nt = 0; nt < 4; ++nt)
#pragma unroll
    for (int r = 0; r < 4; ++r) {
      float v = S[nt][r];
      if (DIAG) v = (nt * 16 + ln <= mrow + r) ? v : -1e30f;
      float pv = exp2f(v - 8.0f);
      int row = quad * 4 + r;
      int chnk = (nt * 2 + (ln >> 3)) ^ (row & 7);
      *(__bf16*)&Pb[row * 64 + chnk * 8 + (ln & 7)] = (__bf16)pv;
    }
}

// ---- causal GQA flash attention: pair-balanced, fixed-rebase softmax ----
// ROUND-8: exact revert to the round-6 structure (72.0us proven). Round-7's
// per-tile inlined emit regressed (76us): ds_writes interleaved between kb
// ds_reads serialize through the in-order lgkm FIFO. Batched emit after the
// QK^T loop keeps the read chain clean.
__global__ __launch_bounds__(256, 2) void k_attn(const u16* __restrict__ Q,
                                                 const u16* __restrict__ Kg,
                                                 const u16* __restrict__ Vt,
                                                 u16* __restrict__ Og) {
  __shared__ __align__(16) u16 Ks[2][64 * 128];   // [key][hd], swizzled chunks
  __shared__ __align__(16) u16 Vs[2][128 * 64];   // [hd][key], swizzled chunks
  __shared__ __align__(16) u16 Ps[4][2][16 * 64]; // per-wave, per-strip P
  const int tid = threadIdx.x;
  const int wv = tid >> 6, lane = tid & 63;
  const int quad = lane >> 4, ln = lane & 15;
  const int bh = blockIdx.y;
  const int b = bh >> 4, h = bh & 15;
  const int kvh = h >> 2;
  const int p = blockIdx.x;
  const int thi = 31 - p, tlo = p;
  const int qhi = thi * 64 + wv * 16;   // global q-row base, hi strip
  const int qlo = tlo * 64 + wv * 16;

  bf16x8 qfh[4], qfl[4];
  {
    const u16* qp = Q + ((long)bh * T_SEQ + qhi + ln) * HD + quad * 8;
#pragma unroll
    for (int s = 0; s < 4; ++s) qfh[s] = *(const bf16x8*)(qp + s * 32);
    qp = Q + ((long)bh * T_SEQ + qlo + ln) * HD + quad * 8;
#pragma unroll
    for (int s = 0; s < 4; ++s) qfl[s] = *(const bf16x8*)(qp + s * 32);
  }
  bf16x8 onesb;
#pragma unroll
  for (int i = 0; i < 8; ++i) onesb[i] = (__bf16)1.0f;

  f32x4 lh = {0.f, 0.f, 0.f, 0.f}, ll = {0.f, 0.f, 0.f, 0.f};
  f32x4 oh[8] = {}, ol[8] = {};

  const u16* Kb = Kg + (long)(b * NKV + kvh) * T_SEQ * HD;
  const u16* Vb = Vt + (long)(b * NKV + kvh) * HD * T_SEQ;

  auto stageKV = [&](int kt, int idx) {
    const int k0 = kt * 64;
#pragma unroll
    for (int r = 0; r < 4; ++r) {
      int s = r * 256 + tid;
      gl_lds16(Kb + (long)(k0 + (s >> 4)) * HD + (((s & 15) ^ ((s >> 4) & 15)) << 3),
               &Ks[idx][(r * 256 + wv * 64) * 8]);
      gl_lds16(Vb + (long)(s >> 3) * T_SEQ + k0 + (((s & 7) ^ ((s >> 3) & 7)) << 3),
               &Vs[idx][(r * 256 + wv * 64) * 8]);
    }
  };

  stageKV(0, 0);
  asm volatile("s_waitcnt vmcnt(0)" ::: "memory");
  __builtin_amdgcn_s_barrier();

  for (int kt = 0; kt <= thi; ++kt) {
    const int cur = kt & 1;
    if (kt < thi) stageKV(kt + 1, cur ^ 1);
    const u16* Ksc = Ks[cur];
    const u16* Vsc = Vs[cur];
    const bool lo_act = (kt <= tlo);
    f32x4 Sh[4], Sl[4];
    __builtin_amdgcn_s_setprio(1);
#pragma unroll
    for (int nt = 0; nt < 4; ++nt) {
      bf16x8 kb[4];
      const u16* kp = &Ksc[(nt * 16 + ln) * 128];
#pragma unroll
      for (int ss = 0; ss < 4; ++ss)
        kb[ss] = *(const bf16x8*)(kp + (((quad + 4 * ss) ^ ln) << 3));
      f32x4 s = {0.f, 0.f, 0.f, 0.f};
#pragma unroll
      for (int ss = 0; ss < 4; ++ss)
        s = __builtin_amdgcn_mfma_f32_16x16x32_bf16(qfh[ss], kb[ss], s, 0, 0, 0);
      Sh[nt] = s;
      if (lo_act) {
        f32x4 t = {0.f, 0.f, 0.f, 0.f};
#pragma unroll
        for (int ss = 0; ss < 4; ++ss)
          t = __builtin_amdgcn_mfma_f32_16x16x32_bf16(qfl[ss], kb[ss], t, 0, 0, 0);
        Sl[nt] = t;
      }
    }
    __builtin_amdgcn_s_setprio(0);
    if (kt == thi) p_emit<true>(Sh, &Ps[wv][0][0], quad, ln, wv * 16 + quad * 4);
    else           p_emit<false>(Sh, &Ps[wv][0][0], quad, ln, 0);
    if (lo_act) {
      if (kt == tlo) p_emit<true>(Sl, &Ps[wv][1][0], quad, ln, wv * 16 + quad * 4);
      else           p_emit<false>(Sl, &Ps[wv][1][0], quad, ln, 0);
    }
    asm volatile("s_waitcnt lgkmcnt(0)" ::: "memory");
    bf16x8 pfh[2], pfl[2];
#pragma unroll
    for (int ss = 0; ss < 2; ++ss)
      pfh[ss] = *(const bf16x8*)&Ps[wv][0][ln * 64 + (((ss * 4 + quad) ^ (ln & 7)) << 3)];
    if (lo_act) {
#pragma unroll
      for (int ss = 0; ss < 2; ++ss)
        pfl[ss] = *(const bf16x8*)&Ps[wv][1][ln * 64 + (((ss * 4 + quad) ^ (ln & 7)) << 3)];
    }
    __builtin_amdgcn_s_setprio(1);
    lh = __builtin_amdgcn_mfma_f32_16x16x32_bf16(pfh[0], onesb, lh, 0, 0, 0);
    lh = __builtin_amdgcn_mfma_f32_16x16x32_bf16(pfh[1], onesb, lh, 0, 0, 0);
    if (lo_act) {
      ll = __builtin_amdgcn_mfma_f32_16x16x32_bf16(pfl[0], onesb, ll, 0, 0, 0);
      ll = __builtin_amdgcn_mfma_f32_16x16x32_bf16(pfl[1], onesb, ll, 0, 0, 0);
    }
#pragma unroll
    for (int dt = 0; dt < 8; ++dt) {
      bf16x8 vb[2];
      const u16* vp = &Vsc[(dt * 16 + ln) * 64];
#pragma unroll
      for (int ss = 0; ss < 2; ++ss)
        vb[ss] = *(const bf16x8*)(vp + (((quad + 4 * ss) ^ (ln & 7)) << 3));
#pragma unroll
      for (int ss = 0; ss < 2; ++ss)
        oh[dt] = __builtin_amdgcn_mfma_f32_16x16x32_bf16(pfh[ss], vb[ss], oh[dt], 0, 0, 0);
      if (lo_act) {
#pragma unroll
        for (int ss = 0; ss < 2; ++ss)
          ol[dt] = __builtin_amdgcn_mfma_f32_16x16x32_bf16(pfl[ss], vb[ss], ol[dt], 0, 0, 0);
      }
    }
    __builtin_amdgcn_s_setprio(0);
    asm volatile("s_waitcnt vmcnt(0)" ::: "memory");
    __builtin_amdgcn_s_barrier();
  }
  float rh[4], rl[4];
#pragma unroll
  for (int r = 0; r < 4; ++r) { rh[r] = 1.f / lh[r]; rl[r] = 1.f / ll[r]; }
#pragma unroll
  for (int dt = 0; dt < 8; ++dt)
#pragma unroll
    for (int r = 0; r < 4; ++r) {
      long rowh = (long)b * T_SEQ + qhi + quad * 4 + r;
      long rowl = (long)b * T_SEQ + qlo + quad * 4 + r;
      Og[rowh * (NH * HD) + h * HD + dt * 16 + ln] = f2b(oh[dt][r] * rh[r]);
      Og[rowl * (NH * HD) + h * HD + dt * 16 + ln] = f2b(ol[dt][r] * rl[r]);
    }
}

extern "C" void kernel_launch(void* const* d_in, const int* in_sizes, int n_in,
                              void* d_out, int out_size, void* d_ws, size_t ws_size,
                              hipStream_t stream) {
  const float* x  = (const float*)d_in[0];
  const float* Wq = (const float*)d_in[1];
  const float* Wk = (const float*)d_in[2];
  const float* Wv = (const float*)d_in[3];
  const float* Wo = (const float*)d_in[4];
  float* out = (float*)d_out;
  char* ws = (char*)d_ws;
  // workspace layout (bytes) -- within the original 71.3MB footprint
  u16* WT  = (u16*)(ws + 0);          // [3072][2048] bf16  (Wq^T | Wk^T | Wv^T)
  u16* Wot = (u16*)(ws + 12582912);   // [2048][2048] bf16
  u16* Vc  = (u16*)(ws + 20971520);   // [B,NKV,T,HD] bf16 (4.2MB, pre-transpose V)
  u16* Qn  = (u16*)(ws + 25165824);   // [B,NH,T,HD] bf16 (16.8MB, roped+scaled Q)
  u16* Xb  = (u16*)(ws + 46137344);   // [4096][2048] bf16 x ; later attn output
  u16* Kb  = (u16*)(ws + 62914560);   // [B,NKV,T,HD] bf16 (roped K)
  u16* Vtb = (u16*)(ws + 67108864);   // [B,NKV,HD,T] bf16
  u16* attn = Xb;   // alias: Xb dead after QKV GEMM (rope now fused there)

  // x convert + all weight transposes, one launch
  k_pre<<<18432, 256, 0, stream>>>(x, Wq, Wk, Wv, Wo, Xb, WT, Wot);

  // QKV projection with fused RoPE epilogue: writes Qn, Kb, Vc directly
  k_gemm<1, u16><<<dim3(32, 24), 256, 0, stream>>>(
      Xb, WT, (u16*)nullptr, Qn, Kb, Vc, MROWS, NQKV, DM);

  k_vt<<<dim3(32, 2, 8), 256, 0, stream>>>(Vc, Vtb);

  k_attn<<<dim3(16, 32), 256, 0, stream>>>(Qn, Kb, Vtb, attn);

  // output projection
  k_gemm<0, float><<<dim3(32, 16), 256, 0, stream>>>(
      attn, Wot, out, nullptr, nullptr, nullptr, MROWS, DM, 2048);
}